// Round 1
// baseline (208.634 us; speedup 1.0000x reference)
//
#include <hip/hip_runtime.h>

#define LSEQ 256
#define EMB  256
#define FIL  256
#define K3F  768
#define NLAB 6
#define BATCH 4

// ---------------- gather + transpose: embT[b][e][l] = table[ids[b][l]][e]
__global__ __launch_bounds__(256) void k_gather(const int* __restrict__ ids,
                                                const float* __restrict__ table,
                                                float* __restrict__ embT) {
    int bl = blockIdx.x;            // b*256 + l
    int b = bl >> 8, l = bl & 255;
    int e = threadIdx.x;
    int id = ids[bl];
    embT[((b * EMB + e) << 8) + l] = table[id * EMB + e];
}

// ---------------- weight transpose: wT_k[i][o][t] = w_k[o][i][t]
__global__ __launch_bounds__(256) void k_wprep(const float* __restrict__ w2,
                                               const float* __restrict__ w3,
                                               const float* __restrict__ w4,
                                               float* __restrict__ wT2,
                                               float* __restrict__ wT3,
                                               float* __restrict__ wT4) {
    int n = blockIdx.x * 256 + threadIdx.x;
    if (n < 131072) {                       // k=2: [256][256][2]
        int i = n >> 9, r = n & 511, o = r >> 1, t = r & 1;
        wT2[n] = w2[(o << 9) + (i << 1) + t];
    } else if (n < 131072 + 196608) {       // k=3: [256][256][3]
        int m = n - 131072;
        int i = m / 768, r = m % 768, o = r / 3, t = r % 3;
        wT3[m] = w3[o * 768 + i * 3 + t];
    } else {                                // k=4: [256][256][4]
        int m = n - 327680;
        int i = m >> 10, r = m & 1023, o = r >> 2, t = r & 3;
        wT4[m] = w4[(o << 10) + (i << 2) + t];
    }
}

// ---------------- conv: out[b][c][l], c grouped {0-255:k2, 256-511:k3, 512-767:k4}
template <int K, int PAD, int OC>
__device__ __forceinline__ void conv_body(const float* __restrict__ embT,
                                          const float* __restrict__ wT,
                                          const float* __restrict__ bias,
                                          float* __restrict__ out,
                                          int b, int o0, int gbase) {
    const int l = threadIdx.x;
    float acc[OC];
#pragma unroll
    for (int o = 0; o < OC; ++o) acc[o] = 0.f;
    const float* ec = embT + b * EMB * LSEQ;   // [e][l]
#pragma unroll 4
    for (int i = 0; i < EMB; ++i) {
        float ev[K];
#pragma unroll
        for (int t = 0; t < K; ++t) {
            int r = l + t - PAD;
            ev[t] = (r >= 0 && r < LSEQ) ? ec[i * LSEQ + r] : 0.f;
        }
        const float* wr = wT + (i * FIL + o0) * K;   // uniform -> s_load
#pragma unroll
        for (int o = 0; o < OC; ++o)
#pragma unroll
            for (int t = 0; t < K; ++t)
                acc[o] += ev[t] * wr[o * K + t];
    }
#pragma unroll
    for (int o = 0; o < OC; ++o)
        out[(b * K3F + gbase + o0 + o) * LSEQ + l] = acc[o] + bias[o0 + o];
}

__global__ __launch_bounds__(256) void k_conv(const float* __restrict__ embT,
                                              const float* __restrict__ wT2,
                                              const float* __restrict__ wT3,
                                              const float* __restrict__ wT4,
                                              const float* __restrict__ b2,
                                              const float* __restrict__ b3,
                                              const float* __restrict__ b4,
                                              float* __restrict__ out) {
    // grid: 4 b * 3 g * 64 chunks (OC=4) = 768 blocks
    int idx = blockIdx.x;
    int b = idx / 192;
    int r = idx % 192;
    int g = r / 64;
    int o0 = (r % 64) * 4;
    if (g == 0)      conv_body<2, 0, 4>(embT, wT2, b2, out, b, o0, 0);
    else if (g == 1) conv_body<3, 1, 4>(embT, wT3, b3, out, b, o0, 256);
    else             conv_body<4, 1, 4>(embT, wT4, b4, out, b, o0, 512);
}

// ---------------- fused pair-einsum: for each (b,i,j): p_k = out[b,i,k]*out[b,j,k];
// triple[b,i,j,c] = sum_k p_k tw[c,k] + tb[c];  scores[b,i,j] = sum_k p_k sw[k] + sb
#define KC 128
__global__ __launch_bounds__(256) void k_pair(const float* __restrict__ out,  // [4][768][256]
                                              const float* __restrict__ tw,   // [6][768]
                                              const float* __restrict__ tb,   // [6]
                                              const float* __restrict__ sw,   // [768]
                                              const float* __restrict__ sb,   // [1]
                                              float* __restrict__ dout) {
    __shared__ float ldsI[KC][36];   // pad 36: 16B-aligned rows, stride-2 reads conflict-free
    __shared__ float ldsJ[KC][36];
    int blk = blockIdx.x;            // 4 * 8 * 8
    int b = blk / 64;
    int r = blk % 64;
    int i0 = (r / 8) * 32, j0 = (r % 8) * 32;
    int tid = threadIdx.x;
    int ti = tid & 15, tj = tid >> 4;

    float acc[7][4];
#pragma unroll
    for (int c = 0; c < 7; ++c)
#pragma unroll
        for (int p = 0; p < 4; ++p) acc[c][p] = 0.f;

    const int kl = tid >> 1;             // 0..127
    const int il0 = (tid & 1) * 16;

    for (int kc = 0; kc < K3F; kc += KC) {
        const float* srcI = out + (b * K3F + kc + kl) * LSEQ + i0 + il0;
        const float* srcJ = out + (b * K3F + kc + kl) * LSEQ + j0 + il0;
#pragma unroll
        for (int m = 0; m < 4; ++m) {
            float4 v = *(const float4*)(srcI + 4 * m);
            *(float4*)&ldsI[kl][il0 + 4 * m] = v;
            float4 w = *(const float4*)(srcJ + 4 * m);
            *(float4*)&ldsJ[kl][il0 + 4 * m] = w;
        }
        __syncthreads();
#pragma unroll 8
        for (int kk = 0; kk < KC; ++kk) {
            int k = kc + kk;
            float iv0 = ldsI[kk][2 * ti], iv1 = ldsI[kk][2 * ti + 1];
            float jv0 = ldsJ[kk][2 * tj], jv1 = ldsJ[kk][2 * tj + 1];
            float p00 = iv0 * jv0, p01 = iv0 * jv1, p10 = iv1 * jv0, p11 = iv1 * jv1;
            float swk = sw[k];
            acc[6][0] += p00 * swk; acc[6][1] += p01 * swk;
            acc[6][2] += p10 * swk; acc[6][3] += p11 * swk;
#pragma unroll
            for (int c = 0; c < 6; ++c) {
                float twk = tw[c * K3F + k];
                acc[c][0] += p00 * twk; acc[c][1] += p01 * twk;
                acc[c][2] += p10 * twk; acc[c][3] += p11 * twk;
            }
        }
        __syncthreads();
    }

    float tbv[6];
#pragma unroll
    for (int c = 0; c < 6; ++c) tbv[c] = tb[c];
    float sbv = sb[0];
#pragma unroll
    for (int di = 0; di < 2; ++di)
#pragma unroll
        for (int dj = 0; dj < 2; ++dj) {
            int i = i0 + 2 * ti + di, j = j0 + 2 * tj + dj;
            int p = di * 2 + dj;
            int base = ((b * LSEQ + i) * LSEQ + j) * 6;
#pragma unroll
            for (int c = 0; c < 6; ++c) dout[base + c] = acc[c][p] + tbv[c];
            dout[4 * 256 * 256 * 6 + (b * LSEQ + i) * LSEQ + j] = acc[6][p] + sbv;
        }
}

extern "C" void kernel_launch(void* const* d_in, const int* in_sizes, int n_in,
                              void* d_out, int out_size, void* d_ws, size_t ws_size,
                              hipStream_t stream) {
    const int*   ids   = (const int*)d_in[0];
    const float* table = (const float*)d_in[1];
    const float* w2 = (const float*)d_in[2];
    const float* b2 = (const float*)d_in[3];
    const float* w3 = (const float*)d_in[4];
    const float* b3 = (const float*)d_in[5];
    const float* w4 = (const float*)d_in[6];
    const float* b4 = (const float*)d_in[7];
    const float* tw = (const float*)d_in[8];
    const float* tb = (const float*)d_in[9];
    const float* sw = (const float*)d_in[10];
    const float* sb = (const float*)d_in[11];

    float* ws   = (float*)d_ws;
    float* embT = ws;                 // 262144 floats
    float* out  = ws + 262144;        // 786432 floats
    float* wT2  = ws + 1048576;       // 131072
    float* wT3  = wT2 + 131072;       // 196608
    float* wT4  = wT3 + 196608;       // 262144
    float* dout = (float*)d_out;

    hipLaunchKernelGGL(k_gather, dim3(1024), dim3(256), 0, stream, ids, table, embT);
    hipLaunchKernelGGL(k_wprep,  dim3(2304), dim3(256), 0, stream, w2, w3, w4, wT2, wT3, wT4);
    hipLaunchKernelGGL(k_conv,   dim3(768),  dim3(256), 0, stream, embT, wT2, wT3, wT4, b2, b3, b4, out);
    hipLaunchKernelGGL(k_pair,   dim3(256),  dim3(256), 0, stream, out, tw, tb, sw, sb, dout);
}

// Round 2
// 176.183 us; speedup vs baseline: 1.1842x; 1.1842x over previous
//
#include <hip/hip_runtime.h>
#include <stdint.h>

#define LSEQ 256
#define EMB  256
#define K3F  768
#define SCOFF (4 * 256 * 256 * 6)

typedef short bf16x8 __attribute__((ext_vector_type(8)));
typedef float f32x4  __attribute__((ext_vector_type(4)));

__device__ __forceinline__ uint16_t f2bf(float x) {
    union { float f; uint32_t u; } c; c.f = x;
    uint32_t r = c.u + 0x7fffu + ((c.u >> 16) & 1u);
    return (uint16_t)(r >> 16);
}

// ---------------- gather via LDS transpose: embT[b][e][l] = table[ids[b][l]][e]
__global__ __launch_bounds__(256) void k_gather(const int* __restrict__ ids,
                                                const float* __restrict__ table,
                                                float* __restrict__ embT) {
    __shared__ float X[256][33];
    int blk = blockIdx.x;                 // 4 b * 8 l-chunks
    int b = blk >> 3, l0 = (blk & 7) << 5;
    int tid = threadIdx.x;
    int lt = tid >> 3, e8 = tid & 7;      // 32 l-rows, 8 e-groups
    int id = ids[(b << 8) + l0 + lt];
    const float* row = table + (size_t)id * EMB;
#pragma unroll
    for (int s = 0; s < 8; ++s) {
        int f = e8 + (s << 3);            // float4 index 0..63
        float4 v = *(const float4*)(row + (f << 2));
        X[(f << 2) + 0][lt] = v.x;
        X[(f << 2) + 1][lt] = v.y;
        X[(f << 2) + 2][lt] = v.z;
        X[(f << 2) + 3][lt] = v.w;
    }
    __syncthreads();
    int lc = tid & 31, e0 = tid >> 5;     // 32 l-cols, 8 e-rows per thread
#pragma unroll 4
    for (int s = 0; s < 32; ++s) {
        int e = (e0 << 5) + s;
        embT[((b << 8) + e) * LSEQ + l0 + lc] = X[e][lc];
    }
}

// ---------------- conv: fp32 VALU, LDS-staged padded rows. Epilogue writes
// mode 0: U[b][c][l][k]=bf16(acc*tw_c[k]) (11MB) + VB[b][l][k]=bf16(acc)
// mode 1: outKL[b][k][l]=acc (fp32, for fallback pair kernel)
template <int K, int OC, int UST>
__device__ __forceinline__ void conv_body(float (*xs)[264],
                                          const float* __restrict__ embT,
                                          const float* __restrict__ w,
                                          const float* __restrict__ bias,
                                          const float* __restrict__ tw,
                                          const float* __restrict__ sw,
                                          float* __restrict__ outKL,
                                          uint16_t* __restrict__ VB,
                                          uint16_t* __restrict__ U,
                                          int b, int o0, int gbase, int mode) {
    const int tid = threadIdx.x;
    const int l = tid;
    float acc[OC];
#pragma unroll
    for (int o = 0; o < OC; ++o) acc[o] = 0.f;

    if (tid < 32) {                      // zero pad cols once (persist across chunks)
#pragma unroll
        for (int u = 0; u < 4; ++u) { xs[tid][u] = 0.f; xs[tid][260 + u] = 0.f; }
    }

    const int r = tid >> 3, c8 = tid & 7;
    for (int i0 = 0; i0 < EMB; i0 += 32) {
        __syncthreads();
        const float* src = embT + ((b << 8) + i0 + r) * LSEQ;
#pragma unroll
        for (int s = 0; s < 8; ++s) {
            int f = c8 + (s << 3);       // float4 col 0..63
            float4 v = *(const float4*)(src + (f << 2));
            *(float4*)&xs[r][4 + (f << 2)] = v;   // data at col 4+r (r = seq pos)
        }
        __syncthreads();
#pragma unroll 4
        for (int ii = 0; ii < 32; ++ii) {
            float wv[K];
#pragma unroll
            for (int t = 0; t < K; ++t) wv[t] = xs[ii][3 + UST + l + t];
            const float* wr = w + (i0 + ii) * K;   // uniform -> s_load
#pragma unroll
            for (int o = 0; o < OC; ++o)
#pragma unroll
                for (int t = 0; t < K; ++t)
                    acc[o] += wv[t] * wr[(o0 + o) * (EMB * K) + t];
        }
    }
#pragma unroll
    for (int o = 0; o < OC; ++o) acc[o] += bias[o0 + o];

    if (mode == 0) {
        const int base = ((b << 8) + l) * K3F + gbase + o0;
        {
            union { uint16_t h[OC]; uint32_t d[OC / 2]; } pk;
#pragma unroll
            for (int o = 0; o < OC; ++o) pk.h[o] = f2bf(acc[o]);
            if constexpr (OC == 8) *(uint4*)(VB + base) = *(const uint4*)pk.d;
            else                   *(uint2*)(VB + base) = *(const uint2*)pk.d;
        }
#pragma unroll
        for (int c = 0; c < 7; ++c) {
            const float* twr = (c < 6) ? tw + c * K3F : sw;
            union { uint16_t h[OC]; uint32_t d[OC / 2]; } pk;
#pragma unroll
            for (int o = 0; o < OC; ++o)
                pk.h[o] = f2bf(acc[o] * twr[gbase + o0 + o]);
            uint16_t* dst = U + (size_t)(((b * 7 + c) << 8) + l) * K3F + gbase + o0;
            if constexpr (OC == 8) *(uint4*)dst = *(const uint4*)pk.d;
            else                   *(uint2*)dst = *(const uint2*)pk.d;
        }
    } else {
#pragma unroll
        for (int o = 0; o < OC; ++o)
            outKL[(b * K3F + gbase + o0 + o) * LSEQ + l] = acc[o];
    }
}

__global__ __launch_bounds__(256) void k_conv(const float* __restrict__ embT,
                                              const float* __restrict__ w2, const float* __restrict__ b2,
                                              const float* __restrict__ w3, const float* __restrict__ b3,
                                              const float* __restrict__ w4, const float* __restrict__ b4,
                                              const float* __restrict__ tw, const float* __restrict__ sw,
                                              float* __restrict__ outKL,
                                              uint16_t* __restrict__ VB,
                                              uint16_t* __restrict__ U, int mode) {
    __shared__ float xs[32][264];
    int blk = blockIdx.x;                 // 4 b * 128 grp
    int b = blk >> 7, grp = blk & 127;
    if (grp < 32)
        conv_body<2, 8, 1>(xs, embT, w2, b2, tw, sw, outKL, VB, U, b, grp << 3, 0, mode);
    else if (grp < 64)
        conv_body<3, 8, 0>(xs, embT, w3, b3, tw, sw, outKL, VB, U, b, (grp - 32) << 3, 256, mode);
    else
        conv_body<4, 4, 0>(xs, embT, w4, b4, tw, sw, outKL, VB, U, b, (grp - 64) << 2, 512, mode);
}

// ---------------- MFMA GEMM: C[i,j] = sum_k U[b,c,i,k] * VB[b,j,k]  (NT, bf16)
__global__ __launch_bounds__(256) void k_gemm(const uint16_t* __restrict__ U,
                                              const uint16_t* __restrict__ VB,
                                              const float* __restrict__ tb,
                                              const float* __restrict__ sb,
                                              float* __restrict__ dout) {
    __shared__ uint16_t As[64][72];       // row stride 144B -> 2-way (free) on b128 reads
    __shared__ uint16_t Bs[64][72];
    int blk = blockIdx.x;                 // 448 = 4b * 16tiles * 7c
    int c = blk % 7;
    int t = (blk / 7) & 15;
    int b = blk / 112;
    int i0 = (t >> 2) << 6, j0 = (t & 3) << 6;
    int tid = threadIdx.x;
    int wave = tid >> 6, lane = tid & 63;
    int wi = (wave >> 1) << 5, wj = (wave & 1) << 5;
    int m = lane & 15, q = lane >> 4;

    const uint16_t* Abase = U + (size_t)(((b * 7 + c) << 8) + i0) * K3F;
    const uint16_t* Bbase = VB + (size_t)((b << 8) + j0) * K3F;

    f32x4 acc[2][2];
#pragma unroll
    for (int a = 0; a < 2; ++a)
#pragma unroll
        for (int n = 0; n < 2; ++n)
#pragma unroll
            for (int z = 0; z < 4; ++z) acc[a][n][z] = 0.f;

    const int srow = tid >> 2, part = (tid & 3) << 4;   // 4 threads/row, 16 elems each
    for (int kc = 0; kc < K3F; kc += 64) {
        __syncthreads();
        const uint16_t* ga = Abase + srow * K3F + kc + part;
        const uint16_t* gb = Bbase + srow * K3F + kc + part;
        *(bf16x8*)&As[srow][part]     = *(const bf16x8*)ga;
        *(bf16x8*)&As[srow][part + 8] = *(const bf16x8*)(ga + 8);
        *(bf16x8*)&Bs[srow][part]     = *(const bf16x8*)gb;
        *(bf16x8*)&Bs[srow][part + 8] = *(const bf16x8*)(gb + 8);
        __syncthreads();
#pragma unroll
        for (int kh = 0; kh < 64; kh += 32) {
            bf16x8 a0 = *(const bf16x8*)&As[wi + m][kh + (q << 3)];
            bf16x8 a1 = *(const bf16x8*)&As[wi + 16 + m][kh + (q << 3)];
            bf16x8 v0 = *(const bf16x8*)&Bs[wj + m][kh + (q << 3)];
            bf16x8 v1 = *(const bf16x8*)&Bs[wj + 16 + m][kh + (q << 3)];
            acc[0][0] = __builtin_amdgcn_mfma_f32_16x16x32_bf16(a0, v0, acc[0][0], 0, 0, 0);
            acc[0][1] = __builtin_amdgcn_mfma_f32_16x16x32_bf16(a0, v1, acc[0][1], 0, 0, 0);
            acc[1][0] = __builtin_amdgcn_mfma_f32_16x16x32_bf16(a1, v0, acc[1][0], 0, 0, 0);
            acc[1][1] = __builtin_amdgcn_mfma_f32_16x16x32_bf16(a1, v1, acc[1][1], 0, 0, 0);
        }
    }

    float bias = (c < 6) ? tb[c] : sb[0];
#pragma unroll
    for (int mt = 0; mt < 2; ++mt)
#pragma unroll
        for (int nt = 0; nt < 2; ++nt)
#pragma unroll
            for (int rg = 0; rg < 4; ++rg) {
                int i = i0 + wi + (mt << 4) + (q << 2) + rg;   // row = quad*4+reg
                int j = j0 + wj + (nt << 4) + m;               // col = lane&15
                float v = acc[mt][nt][rg] + bias;
                if (c < 6) dout[(((b << 8) + i) * 256 + j) * 6 + c] = v;
                else       dout[SCOFF + ((b << 8) + i) * 256 + j] = v;
            }
}

// ---------------- fallback (ws too small): R1's fp32 pair kernel, reads outKL[b][k][l]
#define KC 128
__global__ __launch_bounds__(256) void k_pair_fb(const float* __restrict__ out,
                                                 const float* __restrict__ tw,
                                                 const float* __restrict__ tb,
                                                 const float* __restrict__ sw,
                                                 const float* __restrict__ sb,
                                                 float* __restrict__ dout) {
    __shared__ float ldsI[KC][36];
    __shared__ float ldsJ[KC][36];
    int blk = blockIdx.x;
    int b = blk / 64;
    int r = blk % 64;
    int i0 = (r / 8) * 32, j0 = (r % 8) * 32;
    int tid = threadIdx.x;
    int ti = tid & 15, tj = tid >> 4;
    float acc[7][4];
#pragma unroll
    for (int c = 0; c < 7; ++c)
#pragma unroll
        for (int p = 0; p < 4; ++p) acc[c][p] = 0.f;
    const int kl = tid >> 1;
    const int il0 = (tid & 1) * 16;
    for (int kc = 0; kc < K3F; kc += KC) {
        const float* srcI = out + (b * K3F + kc + kl) * LSEQ + i0 + il0;
        const float* srcJ = out + (b * K3F + kc + kl) * LSEQ + j0 + il0;
#pragma unroll
        for (int m = 0; m < 4; ++m) {
            *(float4*)&ldsI[kl][il0 + 4 * m] = *(const float4*)(srcI + 4 * m);
            *(float4*)&ldsJ[kl][il0 + 4 * m] = *(const float4*)(srcJ + 4 * m);
        }
        __syncthreads();
#pragma unroll 8
        for (int kk = 0; kk < KC; ++kk) {
            int k = kc + kk;
            float iv0 = ldsI[kk][2 * ti], iv1 = ldsI[kk][2 * ti + 1];
            float jv0 = ldsJ[kk][2 * tj], jv1 = ldsJ[kk][2 * tj + 1];
            float p00 = iv0 * jv0, p01 = iv0 * jv1, p10 = iv1 * jv0, p11 = iv1 * jv1;
            float swk = sw[k];
            acc[6][0] += p00 * swk; acc[6][1] += p01 * swk;
            acc[6][2] += p10 * swk; acc[6][3] += p11 * swk;
#pragma unroll
            for (int c = 0; c < 6; ++c) {
                float twk = tw[c * K3F + k];
                acc[c][0] += p00 * twk; acc[c][1] += p01 * twk;
                acc[c][2] += p10 * twk; acc[c][3] += p11 * twk;
            }
        }
        __syncthreads();
    }
    float tbv[6];
#pragma unroll
    for (int c = 0; c < 6; ++c) tbv[c] = tb[c];
    float sbv = sb[0];
#pragma unroll
    for (int di = 0; di < 2; ++di)
#pragma unroll
        for (int dj = 0; dj < 2; ++dj) {
            int i = i0 + 2 * ti + di, j = j0 + 2 * tj + dj;
            int p = di * 2 + dj;
            int base = ((b * LSEQ + i) * LSEQ + j) * 6;
#pragma unroll
            for (int c = 0; c < 6; ++c) dout[base + c] = acc[c][p] + tbv[c];
            dout[SCOFF + (b * LSEQ + i) * LSEQ + j] = acc[6][p] + sbv;
        }
}

extern "C" void kernel_launch(void* const* d_in, const int* in_sizes, int n_in,
                              void* d_out, int out_size, void* d_ws, size_t ws_size,
                              hipStream_t stream) {
    const int*   ids   = (const int*)d_in[0];
    const float* table = (const float*)d_in[1];
    const float* w2 = (const float*)d_in[2];
    const float* b2 = (const float*)d_in[3];
    const float* w3 = (const float*)d_in[4];
    const float* b3 = (const float*)d_in[5];
    const float* w4 = (const float*)d_in[6];
    const float* b4 = (const float*)d_in[7];
    const float* tw = (const float*)d_in[8];
    const float* tb = (const float*)d_in[9];
    const float* sw = (const float*)d_in[10];
    const float* sb = (const float*)d_in[11];
    float* dout = (float*)d_out;

    uint8_t* wsb = (uint8_t*)d_ws;
    float*    embT  = (float*)wsb;                      // 1,048,576 B
    float*    outKL = (float*)(wsb + 1048576);          // 3,145,728 B (fallback only)
    uint16_t* VB    = (uint16_t*)(wsb + 4194304);       // 1,572,864 B
    uint16_t* U     = (uint16_t*)(wsb + 5767168);       // 11,010,048 B -> 16 MiB total
    const int mode = (ws_size >= (size_t)16777216) ? 0 : 1;

    hipLaunchKernelGGL(k_gather, dim3(32), dim3(256), 0, stream, ids, table, embT);
    hipLaunchKernelGGL(k_conv, dim3(512), dim3(256), 0, stream,
                       embT, w2, b2, w3, b3, w4, b4, tw, sw, outKL, VB, U, mode);
    if (mode == 0)
        hipLaunchKernelGGL(k_gemm, dim3(448), dim3(256), 0, stream, U, VB, tb, sb, dout);
    else
        hipLaunchKernelGGL(k_pair_fb, dim3(256), dim3(256), 0, stream,
                           outKL, tw, tb, sw, sb, dout);
}

// Round 3
// 134.903 us; speedup vs baseline: 1.5466x; 1.3060x over previous
//
#include <hip/hip_runtime.h>
#include <stdint.h>

#define LSEQ 256
#define EMB  256
#define K3F  768
#define SCOFF (4 * 256 * 256 * 6)

typedef short bf16x8 __attribute__((ext_vector_type(8)));
typedef float f32x4  __attribute__((ext_vector_type(4)));

__device__ __forceinline__ uint16_t f2bf(float x) {
    union { float f; uint32_t u; } c; c.f = x;
    uint32_t r = c.u + 0x7fffu + ((c.u >> 16) & 1u);
    return (uint16_t)(r >> 16);
}

// ---------- gather: embB[b][272][256] bf16, data at row 4+l, zero pad rows
__global__ __launch_bounds__(256) void k_gather(const int* __restrict__ ids,
                                                const float* __restrict__ table,
                                                uint16_t* __restrict__ embB) {
    int blk = blockIdx.x, tid = threadIdx.x;
    if (blk < 32) {
        int b = blk >> 3, l0 = (blk & 7) << 5;
        int r = tid >> 3, p = tid & 7;                 // 32 rows x 8 thr (32 e each)
        int id = ids[(b << 8) + l0 + r];
        const float* src = table + (size_t)id * EMB + p * 32;
        uint16_t* dst = embB + (size_t)(b * 272 + 4 + l0 + r) * 256 + p * 32;
#pragma unroll
        for (int s = 0; s < 8; ++s) {
            float4 v = *(const float4*)(src + 4 * s);
            uint32_t lo = f2bf(v.x) | ((uint32_t)f2bf(v.y) << 16);
            uint32_t hi = f2bf(v.z) | ((uint32_t)f2bf(v.w) << 16);
            *(uint2*)(dst + 4 * s) = make_uint2(lo, hi);
        }
    } else {                                           // zero pad rows 0..3, 260..271
        int b = blk - 32;
        int ri = tid >> 4;
        int row = ri < 4 ? ri : 256 + ri;
        int off = (tid & 15) * 16;
        uint16_t* dst = embB + (size_t)(b * 272 + row) * 256 + off;
        *(uint4*)dst = make_uint4(0, 0, 0, 0);
        *(uint4*)(dst + 8) = make_uint4(0, 0, 0, 0);
    }
}

// ---------- weight prep: Wt_k[t][c][i] bf16 from w_k[c][i][t] fp32
__global__ __launch_bounds__(256) void k_wprep(const float* __restrict__ w2,
                                               const float* __restrict__ w3,
                                               const float* __restrict__ w4,
                                               uint16_t* __restrict__ Wt2,
                                               uint16_t* __restrict__ Wt3,
                                               uint16_t* __restrict__ Wt4) {
    int n = blockIdx.x * 256 + threadIdx.x;
    if (n < 131072) {
        int t = n >> 16, rem = n & 65535, c = rem >> 8, i = rem & 255;
        Wt2[n] = f2bf(w2[(c << 9) + (i << 1) + t]);
    } else if (n < 327680) {
        int m = n - 131072;
        int t = m >> 16, rem = m & 65535, c = rem >> 8, i = rem & 255;
        Wt3[m] = f2bf(w3[c * 768 + i * 3 + t]);
    } else if (n < 589824) {
        int m = n - 327680;
        int t = m >> 16, rem = m & 65535, c = rem >> 8, i = rem & 255;
        Wt4[m] = f2bf(w4[(c << 10) + (i << 2) + t]);
    }
}

// ---------- conv as MFMA GEMM over shifts; epilogue emits VB + 7 scaled U copies
template <int K, int PAD>
__device__ __forceinline__ void convg_body(const uint16_t* __restrict__ Wt,
                                           const float* __restrict__ bias,
                                           const uint16_t* __restrict__ embB,
                                           const float* __restrict__ tw,
                                           const float* __restrict__ sw,
                                           uint16_t* __restrict__ VB,
                                           uint16_t* __restrict__ U,
                                           int b, int c0, int l0, int gbase,
                                           uint16_t (*As)[36], uint16_t (*Bs)[36],
                                           float (*twb)[64]) {
    const int tid = threadIdx.x;
    for (int idx = tid; idx < 512; idx += 256) {       // stage tw rows + bias
        int cm = idx >> 6, cc = idx & 63;
        int gch = gbase + c0 + cc;
        float v;
        if (cm < 6) v = tw[cm * K3F + gch];
        else if (cm == 6) v = sw[gch];
        else v = bias[c0 + cc];
        twb[cm][cc] = v;
    }
    const int lane = tid & 63, wave = tid >> 6;
    const int wm = wave >> 1, wn = wave & 1;
    const int m = lane & 15, q = lane >> 4;
    const int qs = tid & 3, r0 = tid >> 2;

    f32x4 acc[2][2];
#pragma unroll
    for (int a = 0; a < 2; ++a)
#pragma unroll
        for (int n = 0; n < 2; ++n)
#pragma unroll
            for (int z = 0; z < 4; ++z) acc[a][n][z] = 0.f;

    for (int i0 = 0; i0 < EMB; i0 += 32) {
        __syncthreads();
#pragma unroll
        for (int t = 0; t < K; ++t) {                  // A: K*64 rows x 32 i
            const uint16_t* src = Wt + (size_t)((t * 256 + c0 + r0) * 256 + i0) + qs * 8;
            *(bf16x8*)&As[t * 64 + r0][qs * 8] = *(const bf16x8*)src;
        }
        {                                              // B: 72 rows (l0-1 .. l0+70)
            const uint16_t* src = embB + (size_t)(b * 272 + 3 + l0 + r0) * 256 + i0 + qs * 8;
            *(bf16x8*)&Bs[r0][qs * 8] = *(const bf16x8*)src;
            if (tid < 32) {
                int r1 = 64 + r0;
                const uint16_t* s2 = embB + (size_t)(b * 272 + 3 + l0 + r1) * 256 + i0 + qs * 8;
                *(bf16x8*)&Bs[r1][qs * 8] = *(const bf16x8*)s2;
            }
        }
        __syncthreads();
#pragma unroll
        for (int t = 0; t < K; ++t) {
            bf16x8 bfr[2], afr[2];
#pragma unroll
            for (int ns = 0; ns < 2; ++ns)
                bfr[ns] = *(const bf16x8*)&Bs[wn * 32 + ns * 16 + m + t - PAD + 1][q * 8];
#pragma unroll
            for (int ms = 0; ms < 2; ++ms)
                afr[ms] = *(const bf16x8*)&As[t * 64 + wm * 32 + ms * 16 + m][q * 8];
#pragma unroll
            for (int ms = 0; ms < 2; ++ms)
#pragma unroll
                for (int ns = 0; ns < 2; ++ns)
                    acc[ms][ns] = __builtin_amdgcn_mfma_f32_16x16x32_bf16(
                        afr[ms], bfr[ns], acc[ms][ns], 0, 0, 0);
        }
    }
    __syncthreads();
    float (*Cs)[68] = (float(*)[68])As;                // reuse As (18432 B >= 17408 B)
#pragma unroll
    for (int ms = 0; ms < 2; ++ms)
#pragma unroll
        for (int ns = 0; ns < 2; ++ns)
#pragma unroll
            for (int rg = 0; rg < 4; ++rg)
                Cs[wm * 32 + ms * 16 + q * 4 + rg][wn * 32 + ns * 16 + m] = acc[ms][ns][rg];
    __syncthreads();
    const int q4 = tid & 3, lw = tid >> 2;             // 16 c per thread, row lw
    float vals[16];
#pragma unroll
    for (int cc = 0; cc < 16; ++cc)
        vals[cc] = Cs[q4 * 16 + cc][lw] + twb[7][q4 * 16 + cc];
    uint16_t pk[16];
#pragma unroll
    for (int cc = 0; cc < 16; ++cc) pk[cc] = f2bf(vals[cc]);
    uint16_t* vdst = VB + (size_t)(b * 256 + l0 + lw) * K3F + gbase + c0 + q4 * 16;
    *(uint4*)vdst = *(uint4*)pk; *(uint4*)(vdst + 8) = *(uint4*)(pk + 8);
#pragma unroll
    for (int cm = 0; cm < 7; ++cm) {
#pragma unroll
        for (int cc = 0; cc < 16; ++cc) pk[cc] = f2bf(vals[cc] * twb[cm][q4 * 16 + cc]);
        uint16_t* udst = U + (size_t)((b * 7 + cm) * 256 + l0 + lw) * K3F + gbase + c0 + q4 * 16;
        *(uint4*)udst = *(uint4*)pk; *(uint4*)(udst + 8) = *(uint4*)(pk + 8);
    }
}

__global__ __launch_bounds__(256) void k_convg(const uint16_t* __restrict__ Wt2,
                                               const uint16_t* __restrict__ Wt3,
                                               const uint16_t* __restrict__ Wt4,
                                               const float* __restrict__ b2,
                                               const float* __restrict__ b3,
                                               const float* __restrict__ b4,
                                               const uint16_t* __restrict__ embB,
                                               const float* __restrict__ tw,
                                               const float* __restrict__ sw,
                                               uint16_t* __restrict__ VB,
                                               uint16_t* __restrict__ U) {
    __shared__ uint16_t As[256][36];
    __shared__ uint16_t Bs[72][36];
    __shared__ float twb[8][64];
    int blk = blockIdx.x;                              // 192 = 4b * 3g * 4c * 4l
    int b = blk & 3, rest = blk >> 2;
    int g = rest >> 4, rt = rest & 15;
    int c0 = (rt >> 2) * 64, l0 = (rt & 3) * 64;
    if (g == 0)      convg_body<2, 0>(Wt2, b2, embB, tw, sw, VB, U, b, c0, l0, 0,   As, Bs, twb);
    else if (g == 1) convg_body<3, 1>(Wt3, b3, embB, tw, sw, VB, U, b, c0, l0, 256, As, Bs, twb);
    else             convg_body<4, 1>(Wt4, b4, embB, tw, sw, VB, U, b, c0, l0, 512, As, Bs, twb);
}

// ---------- pair GEMM: block = (b, i-tile 32, j-tile 32), all 7 c share tiles
__global__ __launch_bounds__(256) void k_pair2(const uint16_t* __restrict__ U,
                                               const uint16_t* __restrict__ VB,
                                               const float* __restrict__ tb,
                                               const float* __restrict__ sb,
                                               float* __restrict__ dout) {
    __shared__ uint16_t T[8][32][36];                  // 0..6 = U c-tiles, 7 = VB
    __shared__ float eps[32][32][8];
    int blk = blockIdx.x;                              // 256 = 4b * 8i * 8j
    int it = blk & 7, jt = (blk >> 3) & 7, b = blk >> 6;   // XCD swizzle: xcd ~ blk%8 = i-tile
    int i0 = it * 32, j0 = jt * 32;
    int tid = threadIdx.x;
    int lane = tid & 63, wave = tid >> 6;
    int ms = wave >> 1, ns = wave & 1;
    int m = lane & 15, q = lane >> 4;
    int qs = tid & 3, rr = tid >> 2;                   // 64 row-slots per pass

    f32x4 acc[7];
#pragma unroll
    for (int c = 0; c < 7; ++c)
#pragma unroll
        for (int z = 0; z < 4; ++z) acc[c][z] = 0.f;

    for (int kc = 0; kc < K3F; kc += 32) {
        __syncthreads();
#pragma unroll
        for (int p = 0; p < 4; ++p) {
            int gr = p * 64 + rr;
            int tile = gr >> 5, row = gr & 31;
            const uint16_t* src = (tile < 7)
                ? U + (size_t)((b * 7 + tile) * 256 + i0 + row) * K3F + kc + qs * 8
                : VB + (size_t)(b * 256 + j0 + row) * K3F + kc + qs * 8;
            *(bf16x8*)&T[tile][row][qs * 8] = *(const bf16x8*)src;
        }
        __syncthreads();
        bf16x8 bfr = *(const bf16x8*)&T[7][ns * 16 + m][q * 8];
#pragma unroll
        for (int c = 0; c < 7; ++c) {
            bf16x8 afr = *(const bf16x8*)&T[c][ms * 16 + m][q * 8];
            acc[c] = __builtin_amdgcn_mfma_f32_16x16x32_bf16(afr, bfr, acc[c], 0, 0, 0);
        }
    }
#pragma unroll
    for (int c = 0; c < 7; ++c)
#pragma unroll
        for (int rg = 0; rg < 4; ++rg)
            eps[ms * 16 + q * 4 + rg][ns * 16 + m][c] = acc[c][rg];
    __syncthreads();
    int iw = tid >> 3, jg = tid & 7;
    float tbv[6];
#pragma unroll
    for (int c = 0; c < 6; ++c) tbv[c] = tb[c];
    float sbv = sb[0];
#pragma unroll
    for (int jj = 0; jj < 4; ++jj) {
        int j = jg * 4 + jj;
        size_t base = ((size_t)((b * 256 + i0 + iw) * 256) + j0 + j) * 6;
        *(float2*)(dout + base)     = make_float2(eps[iw][j][0] + tbv[0], eps[iw][j][1] + tbv[1]);
        *(float2*)(dout + base + 2) = make_float2(eps[iw][j][2] + tbv[2], eps[iw][j][3] + tbv[3]);
        *(float2*)(dout + base + 4) = make_float2(eps[iw][j][4] + tbv[4], eps[iw][j][5] + tbv[5]);
        dout[SCOFF + (b * 256 + i0 + iw) * 256 + j0 + j] = eps[iw][j][6] + sbv;
    }
}

extern "C" void kernel_launch(void* const* d_in, const int* in_sizes, int n_in,
                              void* d_out, int out_size, void* d_ws, size_t ws_size,
                              hipStream_t stream) {
    const int*   ids   = (const int*)d_in[0];
    const float* table = (const float*)d_in[1];
    const float* w2 = (const float*)d_in[2];
    const float* b2 = (const float*)d_in[3];
    const float* w3 = (const float*)d_in[4];
    const float* b3 = (const float*)d_in[5];
    const float* w4 = (const float*)d_in[6];
    const float* b4 = (const float*)d_in[7];
    const float* tw = (const float*)d_in[8];
    const float* tb = (const float*)d_in[9];
    const float* sw = (const float*)d_in[10];
    const float* sb = (const float*)d_in[11];
    float* dout = (float*)d_out;

    uint8_t* wsb = (uint8_t*)d_ws;
    uint16_t* embB = (uint16_t*)(wsb + 0);             //   557,056 B
    uint16_t* Wt2  = (uint16_t*)(wsb + 557056);        //   262,144 B
    uint16_t* Wt3  = (uint16_t*)(wsb + 819200);        //   393,216 B
    uint16_t* Wt4  = (uint16_t*)(wsb + 1212416);       //   524,288 B
    uint16_t* VB   = (uint16_t*)(wsb + 1736704);       // 1,572,864 B
    uint16_t* U    = (uint16_t*)(wsb + 3309568);       // 11,010,048 B -> 14,319,616 total

    hipLaunchKernelGGL(k_gather, dim3(36),   dim3(256), 0, stream, ids, table, embB);
    hipLaunchKernelGGL(k_wprep,  dim3(2304), dim3(256), 0, stream, w2, w3, w4, Wt2, Wt3, Wt4);
    hipLaunchKernelGGL(k_convg,  dim3(192),  dim3(256), 0, stream,
                       Wt2, Wt3, Wt4, b2, b3, b4, embB, tw, sw, VB, U);
    hipLaunchKernelGGL(k_pair2,  dim3(256),  dim3(256), 0, stream, U, VB, tb, sb, dout);
}

// Round 4
// 113.378 us; speedup vs baseline: 1.8402x; 1.1898x over previous
//
#include <hip/hip_runtime.h>
#include <stdint.h>

#define LSEQ 256
#define EMB  256
#define K3F  768
#define SCOFF (4 * 256 * 256 * 6)

typedef short bf16x8 __attribute__((ext_vector_type(8)));
typedef float f32x4  __attribute__((ext_vector_type(4)));

__device__ __forceinline__ uint16_t f2bf(float x) {
    union { float f; uint32_t u; } c; c.f = x;
    uint32_t r = c.u + 0x7fffu + ((c.u >> 16) & 1u);
    return (uint16_t)(r >> 16);
}

// ---------- prep: gather->embB bf16 (rows 4+l, zero halo), wprep->Wt[t][c][i] bf16
__global__ __launch_bounds__(256) void k_prep(const int* __restrict__ ids,
                                              const float* __restrict__ table,
                                              const float* __restrict__ w2,
                                              const float* __restrict__ w3,
                                              const float* __restrict__ w4,
                                              uint16_t* __restrict__ embB,
                                              uint16_t* __restrict__ Wt2,
                                              uint16_t* __restrict__ Wt3,
                                              uint16_t* __restrict__ Wt4) {
    int blk = blockIdx.x, tid = threadIdx.x;
    if (blk < 32) {                       // gather: 4b x 8 l-chunks of 32
        int b = blk >> 3, l0 = (blk & 7) << 5;
        int r = tid >> 3, p = tid & 7;
        int id = ids[(b << 8) + l0 + r];
        const float* src = table + (size_t)id * EMB + p * 32;
        uint16_t* dst = embB + (size_t)(b * 272 + 4 + l0 + r) * 256 + p * 32;
#pragma unroll
        for (int s = 0; s < 8; ++s) {
            float4 v = *(const float4*)(src + 4 * s);
            uint32_t lo = f2bf(v.x) | ((uint32_t)f2bf(v.y) << 16);
            uint32_t hi = f2bf(v.z) | ((uint32_t)f2bf(v.w) << 16);
            *(uint2*)(dst + 4 * s) = make_uint2(lo, hi);
        }
    } else if (blk < 36) {                // zero pad rows 0..3, 260..271
        int b = blk - 32;
        int ri = tid >> 4;
        int row = ri < 4 ? ri : 256 + ri;
        int off = (tid & 15) * 16;
        uint16_t* dst = embB + (size_t)(b * 272 + row) * 256 + off;
        *(uint4*)dst = make_uint4(0, 0, 0, 0);
        *(uint4*)(dst + 8) = make_uint4(0, 0, 0, 0);
    } else {                              // wprep
        int n = (blk - 36) * 256 + tid;
        if (n < 131072) {
            int t = n >> 16, rem = n & 65535, c = rem >> 8, i = rem & 255;
            Wt2[n] = f2bf(w2[(c << 9) + (i << 1) + t]);
        } else if (n < 327680) {
            int m = n - 131072;
            int t = m >> 16, rem = m & 65535, c = rem >> 8, i = rem & 255;
            Wt3[m] = f2bf(w3[c * 768 + i * 3 + t]);
        } else if (n < 589824) {
            int m = n - 327680;
            int t = m >> 16, rem = m & 65535, c = rem >> 8, i = rem & 255;
            Wt4[m] = f2bf(w4[(c << 10) + (i << 2) + t]);
        }
    }
}

// ---------- conv as MFMA GEMM, 32c x 32l tiles, i-chunk 64; epilogue VB + 7 U copies
template <int K, int PAD>
__device__ __forceinline__ void convg_body(const uint16_t* __restrict__ Wt,
                                           const float* __restrict__ bias,
                                           const uint16_t* __restrict__ embB,
                                           const float* __restrict__ tw,
                                           const float* __restrict__ sw,
                                           uint16_t* __restrict__ VB,
                                           uint16_t* __restrict__ U,
                                           int b, int c0, int l0, int gbase,
                                           uint16_t (*As)[32][72], uint16_t (*Bs)[72],
                                           float (*twb)[32]) {
    const int tid = threadIdx.x;
    {   // stage tw rows (7) + bias into twb[8][32]
        int cm = tid >> 5, cc = tid & 31;
        int gch = gbase + c0 + cc;
        float v;
        if (cm < 6) v = tw[cm * K3F + gch];
        else if (cm == 6) v = sw[gch];
        else v = bias[c0 + cc];
        twb[cm][cc] = v;
    }
    const int lane = tid & 63, wave = tid >> 6;
    const int ms = wave >> 1, ns = wave & 1;
    const int m = lane & 15, q = lane >> 4;
    const int ar = tid >> 3, aseg = (tid & 7) * 8;

    f32x4 acc;
#pragma unroll
    for (int z = 0; z < 4; ++z) acc[z] = 0.f;

    for (int i0 = 0; i0 < EMB; i0 += 64) {
        __syncthreads();
#pragma unroll
        for (int t = 0; t < K; ++t) {
            const uint16_t* src = Wt + (size_t)((t * 256 + c0 + ar) * 256 + i0) + aseg;
            *(bf16x8*)&As[t][ar][aseg] = *(const bf16x8*)src;
        }
        {   // B rows: embB rows 3+l0 .. 3+l0+35 (36 rows x 64 i)
            const uint16_t* src = embB + (size_t)(b * 272 + 3 + l0 + ar) * 256 + i0 + aseg;
            *(bf16x8*)&Bs[ar][aseg] = *(const bf16x8*)src;
            if (tid < 32) {
                int r2 = 32 + (tid >> 3);
                const uint16_t* s2 = embB + (size_t)(b * 272 + 3 + l0 + r2) * 256 + i0 + aseg;
                *(bf16x8*)&Bs[r2][aseg] = *(const bf16x8*)s2;
            }
        }
        __syncthreads();
#pragma unroll
        for (int t = 0; t < K; ++t) {
#pragma unroll
            for (int kh = 0; kh < 64; kh += 32) {
                bf16x8 afr = *(const bf16x8*)&As[t][ms * 16 + m][kh + q * 8];
                bf16x8 bfr = *(const bf16x8*)&Bs[ns * 16 + m + t - PAD + 1][kh + q * 8];
                acc = __builtin_amdgcn_mfma_f32_16x16x32_bf16(afr, bfr, acc, 0, 0, 0);
            }
        }
    }
    __syncthreads();
    float (*Cs)[36] = (float(*)[36])As;   // 4,608 B reuse
#pragma unroll
    for (int rg = 0; rg < 4; ++rg)
        Cs[ms * 16 + q * 4 + rg][ns * 16 + m] = acc[rg];
    __syncthreads();
    const int l = tid >> 3, cs = (tid & 7) * 4;
    float vals[4];
#pragma unroll
    for (int v = 0; v < 4; ++v) vals[v] = Cs[cs + v][l] + twb[7][cs + v];
    union { uint16_t h[4]; uint32_t d[2]; } pk;
#pragma unroll
    for (int v = 0; v < 4; ++v) pk.h[v] = f2bf(vals[v]);
    uint16_t* vdst = VB + (size_t)(b * 256 + l0 + l) * K3F + gbase + c0 + cs;
    *(uint2*)vdst = *(const uint2*)pk.d;
#pragma unroll
    for (int cm = 0; cm < 7; ++cm) {
#pragma unroll
        for (int v = 0; v < 4; ++v) pk.h[v] = f2bf(vals[v] * twb[cm][cs + v]);
        uint16_t* udst = U + (size_t)((b * 7 + cm) * 256 + l0 + l) * K3F + gbase + c0 + cs;
        *(uint2*)udst = *(const uint2*)pk.d;
    }
}

__global__ __launch_bounds__(256, 2) void k_convg(const uint16_t* __restrict__ Wt2,
                                                  const uint16_t* __restrict__ Wt3,
                                                  const uint16_t* __restrict__ Wt4,
                                                  const float* __restrict__ b2,
                                                  const float* __restrict__ b3,
                                                  const float* __restrict__ b4,
                                                  const uint16_t* __restrict__ embB,
                                                  const float* __restrict__ tw,
                                                  const float* __restrict__ sw,
                                                  uint16_t* __restrict__ VB,
                                                  uint16_t* __restrict__ U) {
    __shared__ uint16_t As[4][32][72];
    __shared__ uint16_t Bs[36][72];
    __shared__ float twb[8][32];
    int blk = blockIdx.x;                 // 768 = 4b * 3g * 8c0 * 8l0
    int b = blk & 3, rest = blk >> 2;
    int g = rest >> 6, rr = rest & 63;
    int c0 = (rr >> 3) * 32, l0 = (rr & 7) * 32;
    if (g == 0)      convg_body<2, 0>(Wt2, b2, embB, tw, sw, VB, U, b, c0, l0, 0,   As, Bs, twb);
    else if (g == 1) convg_body<3, 1>(Wt3, b3, embB, tw, sw, VB, U, b, c0, l0, 256, As, Bs, twb);
    else             convg_body<4, 1>(Wt4, b4, embB, tw, sw, VB, U, b, c0, l0, 512, As, Bs, twb);
}

// ---------- pair GEMM, one (b,c,i-tile,j-tile) per block: 1792 blocks, 7/CU
__global__ __launch_bounds__(256, 4) void k_pairc(const uint16_t* __restrict__ U,
                                                  const uint16_t* __restrict__ VB,
                                                  const float* __restrict__ tb,
                                                  const float* __restrict__ sb,
                                                  float* __restrict__ dout) {
    __shared__ uint16_t T[64][136];       // rows 0..31 = U tile, 32..63 = VB tile
    int blk = blockIdx.x;                 // jt in low bits -> XCD spread
    int jt = blk & 7, it = (blk >> 3) & 7;
    int c = (blk >> 6) % 7, b = blk / 448;
    int i0 = it * 32, j0 = jt * 32;
    int tid = threadIdx.x;
    int lane = tid & 63, wave = tid >> 6;
    int ms = wave >> 1, ns = wave & 1;
    int m = lane & 15, q = lane >> 4;
    int rs = tid >> 2, off = (tid & 3) * 32;   // 64 row-slots x 4 thr (32 halfs each)

    const uint16_t* srcA = U + (size_t)((b * 7 + c) * 256 + i0 + rs) * K3F + off;
    const uint16_t* srcB = VB + (size_t)(b * 256 + j0 + (rs - 32)) * K3F + off;
    const uint16_t* src = (rs < 32) ? srcA : srcB;

    f32x4 acc;
#pragma unroll
    for (int z = 0; z < 4; ++z) acc[z] = 0.f;

    for (int kc = 0; kc < K3F; kc += 128) {
        __syncthreads();
#pragma unroll
        for (int s = 0; s < 4; ++s)
            *(bf16x8*)&T[rs][off + s * 8] = *(const bf16x8*)(src + kc + s * 8);
        __syncthreads();
#pragma unroll
        for (int kh = 0; kh < 4; ++kh) {
            bf16x8 afr = *(const bf16x8*)&T[ms * 16 + m][kh * 32 + q * 8];
            bf16x8 bfr = *(const bf16x8*)&T[32 + ns * 16 + m][kh * 32 + q * 8];
            acc = __builtin_amdgcn_mfma_f32_16x16x32_bf16(afr, bfr, acc, 0, 0, 0);
        }
    }
    float bias = (c < 6) ? tb[c] : sb[0];
#pragma unroll
    for (int rg = 0; rg < 4; ++rg) {
        int i = i0 + ms * 16 + q * 4 + rg;
        int j = j0 + ns * 16 + m;
        float v = acc[rg] + bias;
        if (c < 6) dout[((size_t)(b * 256 + i) * 256 + j) * 6 + c] = v;
        else       dout[SCOFF + (size_t)(b * 256 + i) * 256 + j] = v;
    }
}

extern "C" void kernel_launch(void* const* d_in, const int* in_sizes, int n_in,
                              void* d_out, int out_size, void* d_ws, size_t ws_size,
                              hipStream_t stream) {
    const int*   ids   = (const int*)d_in[0];
    const float* table = (const float*)d_in[1];
    const float* w2 = (const float*)d_in[2];
    const float* b2 = (const float*)d_in[3];
    const float* w3 = (const float*)d_in[4];
    const float* b3 = (const float*)d_in[5];
    const float* w4 = (const float*)d_in[6];
    const float* b4 = (const float*)d_in[7];
    const float* tw = (const float*)d_in[8];
    const float* tb = (const float*)d_in[9];
    const float* sw = (const float*)d_in[10];
    const float* sb = (const float*)d_in[11];
    float* dout = (float*)d_out;

    uint8_t* wsb = (uint8_t*)d_ws;
    uint16_t* embB = (uint16_t*)(wsb + 0);             //   557,056 B
    uint16_t* Wt2  = (uint16_t*)(wsb + 557056);        //   262,144 B
    uint16_t* Wt3  = (uint16_t*)(wsb + 819200);        //   393,216 B
    uint16_t* Wt4  = (uint16_t*)(wsb + 1212416);       //   524,288 B
    uint16_t* VB   = (uint16_t*)(wsb + 1736704);       // 1,572,864 B
    uint16_t* U    = (uint16_t*)(wsb + 3309568);       // 11,010,048 B

    hipLaunchKernelGGL(k_prep,  dim3(2340), dim3(256), 0, stream,
                       ids, table, w2, w3, w4, embB, Wt2, Wt3, Wt4);
    hipLaunchKernelGGL(k_convg, dim3(768),  dim3(256), 0, stream,
                       Wt2, Wt3, Wt4, b2, b3, b4, embB, tw, sw, VB, U);
    hipLaunchKernelGGL(k_pairc, dim3(1792), dim3(256), 0, stream, U, VB, tb, sb, dout);
}